// Round 3
// baseline (100.126 us; speedup 1.0000x reference)
//
#include <hip/hip_runtime.h>
#include <stddef.h>

// NPDCLoss: out[d] = mean_t (x_pred[t,d] - delayed_avg[t,d])^2
//   delayed_avg[t] = (sum_{j=1..m} x_true[t-j] + (NLAG-m)*x_true[t]) / NLAG,
//   m = min(t, NLAG)

#define NS   16384
#define D    2048
#define NLAG 50

#define ROW_CHUNKS     512
#define ROWS_PER_CHUNK (NS / ROW_CHUNKS)    // 32
#define BLOCK          256
#define CPT            2                    // columns per thread (float2)
#define COLS_PER_BLOCK (BLOCK * CPT)        // 512
#define COL_BLOCKS     (D / COLS_PER_BLOCK) // 4

__device__ __forceinline__ float2 ld2(const float* p) {
    return *reinterpret_cast<const float2*>(p);
}

template <bool USE_WS>
__global__ __launch_bounds__(BLOCK) void npdc_partial(
    const float* __restrict__ xp,
    const float* __restrict__ xt,
    float* __restrict__ partial,   // [ROW_CHUNKS][D] when USE_WS
    float* __restrict__ out)       // [D] atomic path when !USE_WS
{
    const int cb  = blockIdx.x;
    const int rc  = blockIdx.y;
    const int col = cb * COLS_PER_BLOCK + (int)threadIdx.x * CPT;
    const int r0  = rc * ROWS_PER_CHUNK;
    const float inv_n = 1.0f / (float)NLAG;

    // ---- warm-up: window sum of rows max(0, r0-NLAG) .. r0-1 ----
    float wx = 0.f, wy = 0.f;
    int jstart = r0 - NLAG;
    if (jstart < 0) jstart = 0;
    #pragma unroll 5
    for (int j = jstart; j < r0; ++j) {
        float2 v = ld2(&xt[(size_t)j * D + col]);
        wx += v.x; wy += v.y;
    }

    float ax = 0.f, ay = 0.f;

    if (r0 >= NLAG) {
        // hot path: branch-free, t-NLAG always valid, fac == 0
        #pragma unroll 8
        for (int t = r0; t < r0 + ROWS_PER_CHUNK; ++t) {
            float2 p = ld2(&xp[(size_t)t * D + col]);
            float2 c = ld2(&xt[(size_t)t * D + col]);
            float2 o = ld2(&xt[(size_t)(t - NLAG) * D + col]);
            float ex = p.x - wx * inv_n;
            float ey = p.y - wy * inv_n;
            ax += ex * ex; ay += ey * ey;
            wx += c.x - o.x; wy += c.y - o.y;
        }
    } else {
        // warm-up chunks (t may be < NLAG)
        for (int t = r0; t < r0 + ROWS_PER_CHUNK; ++t) {
            float2 p = ld2(&xp[(size_t)t * D + col]);
            float2 c = ld2(&xt[(size_t)t * D + col]);
            float fac = (t < NLAG) ? (float)(NLAG - t) : 0.0f;
            float ex = p.x - (wx + fac * c.x) * inv_n;
            float ey = p.y - (wy + fac * c.y) * inv_n;
            ax += ex * ex; ay += ey * ey;
            wx += c.x; wy += c.y;
            if (t >= NLAG) {
                float2 o = ld2(&xt[(size_t)(t - NLAG) * D + col]);
                wx -= o.x; wy -= o.y;
            }
        }
    }

    if (USE_WS) {
        float2 r; r.x = ax; r.y = ay;
        *reinterpret_cast<float2*>(&partial[(size_t)rc * D + col]) = r;
    } else {
        const float inv_ns = 1.0f / (float)NS;
        atomicAdd(&out[col],     ax * inv_ns);
        atomicAdd(&out[col + 1], ay * inv_ns);
    }
}

// Reduce [ROW_CHUNKS][D] -> [D].  Grid: D/64 blocks of 256 threads.
// Each block: 64 columns x 4 chunk-groups (ROW_CHUNKS/4 each) + LDS combine.
__global__ __launch_bounds__(BLOCK) void npdc_reduce(
    const float* __restrict__ partial, float* __restrict__ out)
{
    const int dl = (int)threadIdx.x & 63;
    const int g  = (int)threadIdx.x >> 6;          // 0..3
    const int d  = blockIdx.x * 64 + dl;
    const int c0 = g * (ROW_CHUNKS / 4);

    float s = 0.0f;
    #pragma unroll 16
    for (int c = c0; c < c0 + ROW_CHUNKS / 4; ++c)
        s += partial[(size_t)c * D + d];

    __shared__ float sm[4][64];
    sm[g][dl] = s;
    __syncthreads();
    if (g == 0) {
        float t = sm[0][dl] + sm[1][dl] + sm[2][dl] + sm[3][dl];
        out[d] = t * (1.0f / (float)NS);
    }
}

__global__ __launch_bounds__(BLOCK) void npdc_zero(float* __restrict__ out)
{
    const int d = blockIdx.x * BLOCK + (int)threadIdx.x;
    if (d < D) out[d] = 0.0f;
}

extern "C" void kernel_launch(void* const* d_in, const int* in_sizes, int n_in,
                              void* d_out, int out_size, void* d_ws, size_t ws_size,
                              hipStream_t stream)
{
    const float* xp = (const float*)d_in[0];   // x_pred [NS, D]
    const float* xt = (const float*)d_in[1];   // x_true [NS, D]
    float* out = (float*)d_out;                // [D]

    const size_t ws_needed = (size_t)ROW_CHUNKS * D * sizeof(float);
    dim3 grid(COL_BLOCKS, ROW_CHUNKS);

    if (ws_size >= ws_needed) {
        float* partial = (float*)d_ws;
        npdc_partial<true><<<grid, BLOCK, 0, stream>>>(xp, xt, partial, out);
        npdc_reduce<<<D / 64, BLOCK, 0, stream>>>(partial, out);
    } else {
        npdc_zero<<<(D + BLOCK - 1) / BLOCK, BLOCK, 0, stream>>>(out);
        npdc_partial<false><<<grid, BLOCK, 0, stream>>>(xp, xt, nullptr, out);
    }
}

// Round 5
// 98.002 us; speedup vs baseline: 1.0217x; 1.0217x over previous
//
#include <hip/hip_runtime.h>
#include <stddef.h>

// NPDCLoss: out[d] = mean_t (x_pred[t,d] - delayed_avg[t,d])^2
//   delayed_avg[t] = (sum_{j=1..m} x_true[t-j] + (NLAG-m)*x_true[t]) / NLAG,
//   m = min(t, NLAG)

#define NS   16384
#define D    2048
#define NLAG 50

#define ROW_CHUNKS     512
#define ROWS_PER_CHUNK (NS / ROW_CHUNKS)    // 32
#define BLOCK          256
#define CPT            4                    // columns per thread (float4)
#define COLS_PER_BLOCK (BLOCK * CPT)        // 1024
#define COL_BLOCKS     (D / COLS_PER_BLOCK) // 2
#define BATCH          8                    // rows per load-batch (24 float4 in flight)

typedef float f4 __attribute__((ext_vector_type(4)));

__device__ __forceinline__ f4 ld4(const float* p) {
    return *reinterpret_cast<const f4*>(p);
}
__device__ __forceinline__ f4 ld4nt(const float* p) {
    return __builtin_nontemporal_load(reinterpret_cast<const f4*>(p));
}

template <bool USE_WS>
__global__ __launch_bounds__(BLOCK, 4) void npdc_partial(
    const float* __restrict__ xp,
    const float* __restrict__ xt,
    float* __restrict__ partial,   // [ROW_CHUNKS][D] when USE_WS
    float* __restrict__ out)       // [D] atomic path when !USE_WS
{
    const int cb  = blockIdx.x;
    const int rc  = blockIdx.y;
    const int col = cb * COLS_PER_BLOCK + (int)threadIdx.x * CPT;
    const int r0  = rc * ROWS_PER_CHUNK;
    const float inv_n = 1.0f / (float)NLAG;

    // ---- warm-up: window sum of rows max(0, r0-NLAG) .. r0-1 ----
    float wx = 0.f, wy = 0.f, wz = 0.f, ww = 0.f;
    int jstart = r0 - NLAG;
    if (jstart < 0) jstart = 0;
    #pragma unroll 10
    for (int j = jstart; j < r0; ++j) {
        f4 v = ld4(&xt[(size_t)j * D + col]);
        wx += v.x; wy += v.y; wz += v.z; ww += v.w;
    }

    float ax = 0.f, ay = 0.f, az = 0.f, aw = 0.f;

    if (r0 >= NLAG) {
        // hot path: branch-free. Explicit 8-row load batches: 24 independent
        // float4 loads (96 VGPRs of in-flight data) issued before consumption.
        for (int tb = r0; tb < r0 + ROWS_PER_CHUNK; tb += BATCH) {
            f4 p[BATCH], c[BATCH], o[BATCH];
            #pragma unroll
            for (int k = 0; k < BATCH; ++k) {
                const size_t row = (size_t)(tb + k) * D + col;
                p[k] = ld4nt(&xp[row]);
                c[k] = ld4(&xt[row]);
                o[k] = ld4(&xt[row - (size_t)NLAG * D]);
            }
            #pragma unroll
            for (int k = 0; k < BATCH; ++k) {
                float ex = p[k].x - wx * inv_n;
                float ey = p[k].y - wy * inv_n;
                float ez = p[k].z - wz * inv_n;
                float ew = p[k].w - ww * inv_n;
                ax += ex * ex; ay += ey * ey; az += ez * ez; aw += ew * ew;
                wx += c[k].x - o[k].x; wy += c[k].y - o[k].y;
                wz += c[k].z - o[k].z; ww += c[k].w - o[k].w;
            }
        }
    } else {
        // warm-up chunks (t may be < NLAG) — only a few blocks take this path
        for (int t = r0; t < r0 + ROWS_PER_CHUNK; ++t) {
            f4 p = ld4(&xp[(size_t)t * D + col]);
            f4 c = ld4(&xt[(size_t)t * D + col]);
            float fac = (t < NLAG) ? (float)(NLAG - t) : 0.0f;
            float ex = p.x - (wx + fac * c.x) * inv_n;
            float ey = p.y - (wy + fac * c.y) * inv_n;
            float ez = p.z - (wz + fac * c.z) * inv_n;
            float ew = p.w - (ww + fac * c.w) * inv_n;
            ax += ex * ex; ay += ey * ey; az += ez * ez; aw += ew * ew;
            wx += c.x; wy += c.y; wz += c.z; ww += c.w;
            if (t >= NLAG) {
                f4 o = ld4(&xt[(size_t)(t - NLAG) * D + col]);
                wx -= o.x; wy -= o.y; wz -= o.z; ww -= o.w;
            }
        }
    }

    if (USE_WS) {
        f4 r; r.x = ax; r.y = ay; r.z = az; r.w = aw;
        *reinterpret_cast<f4*>(&partial[(size_t)rc * D + col]) = r;
    } else {
        const float inv_ns = 1.0f / (float)NS;
        atomicAdd(&out[col],     ax * inv_ns);
        atomicAdd(&out[col + 1], ay * inv_ns);
        atomicAdd(&out[col + 2], az * inv_ns);
        atomicAdd(&out[col + 3], aw * inv_ns);
    }
}

// Reduce [ROW_CHUNKS][D] -> [D].  Grid: D/64 blocks of 256 threads.
__global__ __launch_bounds__(BLOCK) void npdc_reduce(
    const float* __restrict__ partial, float* __restrict__ out)
{
    const int dl = (int)threadIdx.x & 63;
    const int g  = (int)threadIdx.x >> 6;          // 0..3
    const int d  = blockIdx.x * 64 + dl;
    const int c0 = g * (ROW_CHUNKS / 4);

    float s = 0.0f;
    #pragma unroll 16
    for (int c = c0; c < c0 + ROW_CHUNKS / 4; ++c)
        s += partial[(size_t)c * D + d];

    __shared__ float sm[4][64];
    sm[g][dl] = s;
    __syncthreads();
    if (g == 0) {
        float t = sm[0][dl] + sm[1][dl] + sm[2][dl] + sm[3][dl];
        out[d] = t * (1.0f / (float)NS);
    }
}

__global__ __launch_bounds__(BLOCK) void npdc_zero(float* __restrict__ out)
{
    const int d = blockIdx.x * BLOCK + (int)threadIdx.x;
    if (d < D) out[d] = 0.0f;
}

extern "C" void kernel_launch(void* const* d_in, const int* in_sizes, int n_in,
                              void* d_out, int out_size, void* d_ws, size_t ws_size,
                              hipStream_t stream)
{
    const float* xp = (const float*)d_in[0];   // x_pred [NS, D]
    const float* xt = (const float*)d_in[1];   // x_true [NS, D]
    float* out = (float*)d_out;                // [D]

    const size_t ws_needed = (size_t)ROW_CHUNKS * D * sizeof(float);
    dim3 grid(COL_BLOCKS, ROW_CHUNKS);

    if (ws_size >= ws_needed) {
        float* partial = (float*)d_ws;
        npdc_partial<true><<<grid, BLOCK, 0, stream>>>(xp, xt, partial, out);
        npdc_reduce<<<D / 64, BLOCK, 0, stream>>>(partial, out);
    } else {
        npdc_zero<<<(D + BLOCK - 1) / BLOCK, BLOCK, 0, stream>>>(out);
        npdc_partial<false><<<grid, BLOCK, 0, stream>>>(xp, xt, nullptr, out);
    }
}

// Round 6
// 65.515 us; speedup vs baseline: 1.5283x; 1.4959x over previous
//
#include <hip/hip_runtime.h>
#include <stddef.h>

// NPDCLoss: out[d] = mean_t (x_pred[t,d] - delayed_avg[t,d])^2
//   delayed_avg[t] = (sum_{j=1..m} x_true[t-j] + (NLAG-m)*x_true[t]) / NLAG
// Lag window held in an LDS ring buffer -> xt read from global exactly once
// (plus 50-row warm-up per chunk). Each thread owns ONE column: no barriers.

#define NS   16384
#define D    2048
#define NLAG 50

#define BLOCK 256
#define COLB  (D / BLOCK)          // 8 column blocks
#define RC    96                   // row chunks  (768 blocks = 3/CU, LDS-bound)
#define BASE_ROWS (NS / RC)        // 170
#define EXTRA (NS - BASE_ROWS*RC)  // 64 chunks get one extra row

template <bool USE_WS>
__global__ __launch_bounds__(BLOCK) void npdc_ring(
    const float* __restrict__ xp,
    const float* __restrict__ xt,
    float* __restrict__ partial,   // [RC][D] when USE_WS
    float* __restrict__ out)       // [D] atomic path when !USE_WS
{
    __shared__ float ring[NLAG][BLOCK];   // 50 KB: last 50 rows of this col stripe
    const int tid = (int)threadIdx.x;
    const int col = blockIdx.x * BLOCK + tid;
    const int rc  = blockIdx.y;
    const int r0  = rc * BASE_ROWS + (rc < EXTRA ? rc : EXTRA);
    const int rows = BASE_ROWS + (rc < EXTRA ? 1 : 0);
    const float inv_n = 1.0f / (float)NLAG;

    float w = 0.f, acc = 0.f;
    int sl = 0;     // ring slot of the next row to pop/push
    int i0 = 0;     // first row index for the batched hot loop

    if (rc == 0) {
        // rows 0..55: growing window (m = min(t,50)); fills ring + w
        for (int t = 0; t < 56; ++t) {
            float cv = xt[(size_t)t * D + col];
            float pv = xp[(size_t)t * D + col];
            float fac = (t < NLAG) ? (float)(NLAG - t) : 0.0f;
            float ov  = (t >= NLAG) ? ring[sl][tid] : 0.0f;
            float e = pv - (w + fac * cv) * inv_n;
            acc += e * e;
            w += cv - ov;
            ring[sl][tid] = cv;
            sl = (sl == NLAG - 1) ? 0 : sl + 1;
        }
        i0 = 56;
    } else {
        // warm-up: rows r0-50 .. r0-1 into ring slots 0..49
        const float* src = &xt[(size_t)(r0 - NLAG) * D + col];
        #pragma unroll 10
        for (int j = 0; j < NLAG; ++j) {
            float v = src[(size_t)j * D];
            w += v;
            ring[j][tid] = v;
        }
        sl = 0;
    }

    // ---- hot loop: batches of 8 rows, full window everywhere ----
    int i = i0;
    for (; i + 8 <= rows; i += 8) {
        float cv[8], pv[8], ov[8];
        const size_t base = (size_t)(r0 + i) * D + col;
        #pragma unroll
        for (int k = 0; k < 8; ++k) {
            cv[k] = xt[base + (size_t)k * D];
            pv[k] = __builtin_nontemporal_load(&xp[base + (size_t)k * D]);
        }
        const int s0 = sl;
        #pragma unroll
        for (int k = 0; k < 8; ++k) {
            int s = s0 + k; s -= (s >= NLAG) ? NLAG : 0;
            ov[k] = ring[s][tid];            // read old BEFORE overwriting
        }
        #pragma unroll
        for (int k = 0; k < 8; ++k) {
            float e = pv[k] - w * inv_n;
            acc += e * e;
            w += cv[k] - ov[k];
            int s = s0 + k; s -= (s >= NLAG) ? NLAG : 0;
            ring[s][tid] = cv[k];
        }
        sl = s0 + 8; sl -= (sl >= NLAG) ? NLAG : 0;
    }
    for (; i < rows; ++i) {   // tail (rows % 8)
        float cv = xt[(size_t)(r0 + i) * D + col];
        float pv = xp[(size_t)(r0 + i) * D + col];
        float ov = ring[sl][tid];
        float e = pv - w * inv_n;
        acc += e * e;
        w += cv - ov;
        ring[sl][tid] = cv;
        sl = (sl == NLAG - 1) ? 0 : sl + 1;
    }

    if (USE_WS) {
        partial[(size_t)rc * D + col] = acc;
    } else {
        atomicAdd(&out[col], acc * (1.0f / (float)NS));
    }
}

// Reduce [RC][D] -> [D].  Grid: D/64 blocks of 256 threads.
__global__ __launch_bounds__(BLOCK) void npdc_reduce(
    const float* __restrict__ partial, float* __restrict__ out)
{
    const int dl = (int)threadIdx.x & 63;
    const int g  = (int)threadIdx.x >> 6;          // 0..3
    const int d  = blockIdx.x * 64 + dl;
    const int c0 = g * (RC / 4);

    float s = 0.0f;
    #pragma unroll 8
    for (int c = c0; c < c0 + RC / 4; ++c)
        s += partial[(size_t)c * D + d];

    __shared__ float sm[4][64];
    sm[g][dl] = s;
    __syncthreads();
    if (g == 0) {
        float t = sm[0][dl] + sm[1][dl] + sm[2][dl] + sm[3][dl];
        out[d] = t * (1.0f / (float)NS);
    }
}

__global__ __launch_bounds__(BLOCK) void npdc_zero(float* __restrict__ out)
{
    const int d = blockIdx.x * BLOCK + (int)threadIdx.x;
    if (d < D) out[d] = 0.0f;
}

extern "C" void kernel_launch(void* const* d_in, const int* in_sizes, int n_in,
                              void* d_out, int out_size, void* d_ws, size_t ws_size,
                              hipStream_t stream)
{
    const float* xp = (const float*)d_in[0];   // x_pred [NS, D]
    const float* xt = (const float*)d_in[1];   // x_true [NS, D]
    float* out = (float*)d_out;                // [D]

    const size_t ws_needed = (size_t)RC * D * sizeof(float);
    dim3 grid(COLB, RC);

    if (ws_size >= ws_needed) {
        float* partial = (float*)d_ws;
        npdc_ring<true><<<grid, BLOCK, 0, stream>>>(xp, xt, partial, out);
        npdc_reduce<<<D / 64, BLOCK, 0, stream>>>(partial, out);
    } else {
        npdc_zero<<<(D + BLOCK - 1) / BLOCK, BLOCK, 0, stream>>>(out);
        npdc_ring<false><<<grid, BLOCK, 0, stream>>>(xp, xt, nullptr, out);
    }
}

// Round 7
// 64.146 us; speedup vs baseline: 1.5609x; 1.0213x over previous
//
#include <hip/hip_runtime.h>
#include <stddef.h>

// NPDCLoss: out[d] = mean_t (x_pred[t,d] - delayed_avg[t,d])^2
//   delayed_avg[t] = (sum_{j=1..m} x_true[t-j] + (NLAG-m)*x_true[t]) / NLAG
// Lag window held in a REGISTER ring (50 VGPRs/thread, all indices static via
// full unroll of 50-row groups). No LDS, no barriers. Chunks of 200 rows.

#define NS   16384
#define D    2048
#define NLAG 50

#define BLOCK 256
#define COLB  (D / BLOCK)      // 8 column blocks
#define CHUNK_ROWS 200
#define RC 82                  // 81 full chunks + last chunk of 184 rows

template <bool USE_WS>
__global__ __launch_bounds__(BLOCK, 4) void npdc_reg(
    const float* __restrict__ xp,
    const float* __restrict__ xt,
    float* __restrict__ partial,   // [RC][D] when USE_WS
    float* __restrict__ out)       // [D] atomic path when !USE_WS
{
    const int tid = (int)threadIdx.x;
    const int col = blockIdx.x * BLOCK + tid;
    const int rc  = blockIdx.y;
    const int r0  = rc * CHUNK_ROWS;
    const int rows = (r0 + CHUNK_ROWS <= NS) ? CHUNK_ROWS : (NS - r0);
    const float inv_n = 1.0f / (float)NLAG;

    const float* xtc = xt + col;
    const float* xpc = xp + col;

    float ring[NLAG];
    float w = 0.f, acc = 0.f;
    int start;

    if (rc == 0) {
        // rows 0..49: growing window, m = t
        #pragma unroll
        for (int t = 0; t < NLAG; ++t) {
            float cv = xtc[(size_t)t * D];
            float pv = xpc[(size_t)t * D];
            float e  = pv - (w + (float)(NLAG - t) * cv) * inv_n;
            acc += e * e;
            w += cv;
            ring[t] = cv;
        }
        start = NLAG;
    } else {
        // warm-up: rows r0-50 .. r0-1 -> ring[0..49]  (r0 % 50 == 0)
        #pragma unroll
        for (int j = 0; j < NLAG; ++j) {
            float v = xtc[(size_t)(r0 - NLAG + j) * D];
            w += v;
            ring[j] = v;
        }
        start = 0;
    }

    // ---- hot loop: full 50-row groups, static ring indices ----
    const int nfull = (rows - start) / NLAG;   // 3 (chunk 0 & last) or 4
    int trow = r0 + start;                     // trow % 50 == 0
    for (int g = 0; g < nfull; ++g) {
        #pragma unroll
        for (int kb = 0; kb < NLAG; kb += 10) {
            float cv[10], pv[10];
            #pragma unroll
            for (int k = 0; k < 10; ++k) {
                const size_t off = (size_t)(trow + kb + k) * D;
                cv[k] = xtc[off];
                pv[k] = __builtin_nontemporal_load(&xpc[off]);
            }
            #pragma unroll
            for (int k = 0; k < 10; ++k) {
                float ov = ring[kb + k];
                float e  = pv[k] - w * inv_n;
                acc += e * e;
                w += cv[k] - ov;
                ring[kb + k] = cv[k];
            }
        }
        trow += NLAG;
    }

    // ---- tail (<50 rows, last chunk only): old value from global ----
    const int tend = r0 + rows;
    for (; trow < tend; ++trow) {
        float cv = xtc[(size_t)trow * D];
        float pv = xpc[(size_t)trow * D];
        float ov = xtc[(size_t)(trow - NLAG) * D];
        float e  = pv - w * inv_n;
        acc += e * e;
        w += cv - ov;
    }

    if (USE_WS) {
        partial[(size_t)rc * D + col] = acc;
    } else {
        atomicAdd(&out[col], acc * (1.0f / (float)NS));
    }
}

// Reduce [RC][D] -> [D].  Grid: D/64 blocks of 256 threads.
__global__ __launch_bounds__(BLOCK) void npdc_reduce(
    const float* __restrict__ partial, float* __restrict__ out)
{
    const int dl = (int)threadIdx.x & 63;
    const int g  = (int)threadIdx.x >> 6;          // 0..3
    const int d  = blockIdx.x * 64 + dl;
    const int c0 = g * 21;
    const int c1 = (c0 + 21 < RC) ? c0 + 21 : RC;

    float s = 0.0f;
    for (int c = c0; c < c1; ++c)
        s += partial[(size_t)c * D + d];

    __shared__ float sm[4][64];
    sm[g][dl] = s;
    __syncthreads();
    if (g == 0) {
        float t = sm[0][dl] + sm[1][dl] + sm[2][dl] + sm[3][dl];
        out[d] = t * (1.0f / (float)NS);
    }
}

__global__ __launch_bounds__(BLOCK) void npdc_zero(float* __restrict__ out)
{
    const int d = blockIdx.x * BLOCK + (int)threadIdx.x;
    if (d < D) out[d] = 0.0f;
}

extern "C" void kernel_launch(void* const* d_in, const int* in_sizes, int n_in,
                              void* d_out, int out_size, void* d_ws, size_t ws_size,
                              hipStream_t stream)
{
    const float* xp = (const float*)d_in[0];   // x_pred [NS, D]
    const float* xt = (const float*)d_in[1];   // x_true [NS, D]
    float* out = (float*)d_out;                // [D]

    const size_t ws_needed = (size_t)RC * D * sizeof(float);
    dim3 grid(COLB, RC);

    if (ws_size >= ws_needed) {
        float* partial = (float*)d_ws;
        npdc_reg<true><<<grid, BLOCK, 0, stream>>>(xp, xt, partial, out);
        npdc_reduce<<<D / 64, BLOCK, 0, stream>>>(partial, out);
    } else {
        npdc_zero<<<(D + BLOCK - 1) / BLOCK, BLOCK, 0, stream>>>(out);
        npdc_reg<false><<<grid, BLOCK, 0, stream>>>(xp, xt, nullptr, out);
    }
}

// Round 8
// 60.448 us; speedup vs baseline: 1.6564x; 1.0612x over previous
//
#include <hip/hip_runtime.h>
#include <stddef.h>

// NPDCLoss: out[d] = mean_t (x_pred[t,d] - delayed_avg[t,d])^2
//   delayed_avg[t] = (sum_{j=1..m} x_true[t-j] + (NLAG-m)*x_true[t]) / NLAG
// Lag-50 window held in 50 NAMED scalar registers (forces SROA -> VGPRs, no
// scratch). All ring indices are compile-time via macro-expanded 50-row groups.

#define NS   16384
#define D    2048
#define NLAG 50

#define BLOCK 256
#define COLB  (D / BLOCK)      // 8 column blocks
#define CHUNK 150              // rows per chunk (multiple-of-50 hot region)
#define RC    110              // 109 full chunks + last chunk of 34 rows

#define DD ((size_t)D)
#define NT(p) __builtin_nontemporal_load(p)

// ---- the 50-register ring, addressed only by name ----
#define RING_DECL \
    float R00,R01,R02,R03,R04,R05,R06,R07,R08,R09, \
          R10,R11,R12,R13,R14,R15,R16,R17,R18,R19, \
          R20,R21,R22,R23,R24,R25,R26,R27,R28,R29, \
          R30,R31,R32,R33,R34,R35,R36,R37,R38,R39, \
          R40,R41,R42,R43,R44,R45,R46,R47,R48,R49;

#define RL0 R00,R01,R02,R03,R04,R05,R06,R07,R08,R09
#define RL1 R10,R11,R12,R13,R14,R15,R16,R17,R18,R19
#define RL2 R20,R21,R22,R23,R24,R25,R26,R27,R28,R29
#define RL3 R30,R31,R32,R33,R34,R35,R36,R37,R38,R39
#define RL4 R40,R41,R42,R43,R44,R45,R46,R47,R48,R49

#define STEPC(pv, cv, R) { float e = (pv) - w * inv_n; acc += e * e; w += (cv) - (R); (R) = (cv); }

// one 10-row batch: 20 loads issued, then 10 compute steps; advances trow
#define C10_IMPL(Ra,Rb,Rc,Rd,Re,Rf,Rg,Rh,Ri,Rj) do { \
    const float* rp = xtc + (size_t)trow * DD; \
    const float* pp = xpc + (size_t)trow * DD; \
    float c0=rp[0*DD], c1=rp[1*DD], c2=rp[2*DD], c3=rp[3*DD], c4=rp[4*DD], \
          c5=rp[5*DD], c6=rp[6*DD], c7=rp[7*DD], c8=rp[8*DD], c9=rp[9*DD]; \
    float p0=NT(pp+0*DD), p1=NT(pp+1*DD), p2=NT(pp+2*DD), p3=NT(pp+3*DD), p4=NT(pp+4*DD), \
          p5=NT(pp+5*DD), p6=NT(pp+6*DD), p7=NT(pp+7*DD), p8=NT(pp+8*DD), p9=NT(pp+9*DD); \
    STEPC(p0,c0,Ra) STEPC(p1,c1,Rb) STEPC(p2,c2,Rc) STEPC(p3,c3,Rd) STEPC(p4,c4,Re) \
    STEPC(p5,c5,Rf) STEPC(p6,c6,Rg) STEPC(p7,c7,Rh) STEPC(p8,c8,Ri) STEPC(p9,c9,Rj) \
    trow += 10; \
} while (0)
#define C10(...) C10_IMPL(__VA_ARGS__)

#define WARM0(t, R) { float cv = xtc[(size_t)(t)*DD]; float pv = xpc[(size_t)(t)*DD]; \
    float e = pv - (w + (float)(NLAG-(t)) * cv) * inv_n; acc += e * e; w += cv; (R) = cv; }

#define WARMU(j, R) { float v = wsrc[(size_t)(j)*DD]; w += v; (R) = v; }

#define DO50(M) \
    M(0,R00) M(1,R01) M(2,R02) M(3,R03) M(4,R04) M(5,R05) M(6,R06) M(7,R07) M(8,R08) M(9,R09) \
    M(10,R10) M(11,R11) M(12,R12) M(13,R13) M(14,R14) M(15,R15) M(16,R16) M(17,R17) M(18,R18) M(19,R19) \
    M(20,R20) M(21,R21) M(22,R22) M(23,R23) M(24,R24) M(25,R25) M(26,R26) M(27,R27) M(28,R28) M(29,R29) \
    M(30,R30) M(31,R31) M(32,R32) M(33,R33) M(34,R34) M(35,R35) M(36,R36) M(37,R37) M(38,R38) M(39,R39) \
    M(40,R40) M(41,R41) M(42,R42) M(43,R43) M(44,R44) M(45,R45) M(46,R46) M(47,R47) M(48,R48) M(49,R49)

template <bool USE_WS>
__global__ __launch_bounds__(BLOCK, 4) void npdc_reg(
    const float* __restrict__ xp,
    const float* __restrict__ xt,
    float* __restrict__ partial,   // [RC][D] when USE_WS
    float* __restrict__ out)       // [D] atomic path when !USE_WS
{
    const int tid = (int)threadIdx.x;
    const int col = blockIdx.x * BLOCK + tid;
    const int rc  = blockIdx.y;
    const int r0  = rc * CHUNK;
    const int rows = (r0 + CHUNK <= NS) ? CHUNK : (NS - r0);
    const float inv_n = 1.0f / (float)NLAG;

    const float* xtc = xt + col;
    const float* xpc = xp + col;

    RING_DECL
    float w = 0.f, acc = 0.f;
    int start, trow;

    if (rc == 0) {
        // rows 0..49: growing window (m = t); fills ring + w
        DO50(WARM0)
        start = NLAG;
    } else {
        // warm-up: rows r0-50 .. r0-1 -> R00..R49
        const float* wsrc = xtc + (size_t)(r0 - NLAG) * DD;
        DO50(WARMU)
        start = 0;
    }

    // ---- hot loop: full 50-row groups, all ring refs by name ----
    const int nfull = (rows - start) / NLAG;
    trow = r0 + start;
    for (int g = 0; g < nfull; ++g) {
        C10(RL0); C10(RL1); C10(RL2); C10(RL3); C10(RL4);
    }

    // ---- tail (<50 rows, last chunk only): old value from global ----
    const int tend = r0 + rows;
    for (; trow < tend; ++trow) {
        float cv = xtc[(size_t)trow * DD];
        float pv = xpc[(size_t)trow * DD];
        float ov = xtc[(size_t)(trow - NLAG) * DD];
        float e  = pv - w * inv_n;
        acc += e * e;
        w += cv - ov;
    }

    if (USE_WS) {
        partial[(size_t)rc * DD + col] = acc;
    } else {
        atomicAdd(&out[col], acc * (1.0f / (float)NS));
    }
}

// Reduce [RC][D] -> [D].  Grid: D/64 blocks of 256 threads.
__global__ __launch_bounds__(BLOCK) void npdc_reduce(
    const float* __restrict__ partial, float* __restrict__ out)
{
    const int dl = (int)threadIdx.x & 63;
    const int g  = (int)threadIdx.x >> 6;          // 0..3
    const int d  = blockIdx.x * 64 + dl;
    const int c0 = g * 28;
    const int c1 = (c0 + 28 < RC) ? c0 + 28 : RC;

    float s = 0.0f;
    for (int c = c0; c < c1; ++c)
        s += partial[(size_t)c * DD + d];

    __shared__ float sm[4][64];
    sm[g][dl] = s;
    __syncthreads();
    if (g == 0) {
        float t = sm[0][dl] + sm[1][dl] + sm[2][dl] + sm[3][dl];
        out[d] = t * (1.0f / (float)NS);
    }
}

__global__ __launch_bounds__(BLOCK) void npdc_zero(float* __restrict__ out)
{
    const int d = blockIdx.x * BLOCK + (int)threadIdx.x;
    if (d < D) out[d] = 0.0f;
}

extern "C" void kernel_launch(void* const* d_in, const int* in_sizes, int n_in,
                              void* d_out, int out_size, void* d_ws, size_t ws_size,
                              hipStream_t stream)
{
    const float* xp = (const float*)d_in[0];   // x_pred [NS, D]
    const float* xt = (const float*)d_in[1];   // x_true [NS, D]
    float* out = (float*)d_out;                // [D]

    const size_t ws_needed = (size_t)RC * D * sizeof(float);
    dim3 grid(COLB, RC);

    if (ws_size >= ws_needed) {
        float* partial = (float*)d_ws;
        npdc_reg<true><<<grid, BLOCK, 0, stream>>>(xp, xt, partial, out);
        npdc_reduce<<<D / 64, BLOCK, 0, stream>>>(partial, out);
    } else {
        npdc_zero<<<(D + BLOCK - 1) / BLOCK, BLOCK, 0, stream>>>(out);
        npdc_reg<false><<<grid, BLOCK, 0, stream>>>(xp, xt, nullptr, out);
    }
}